// Round 23
// baseline (211.139 us; speedup 1.0000x reference)
//
#include <hip/hip_runtime.h>
#include <hip/hip_bf16.h>

#define N_NODES 65536
#define N_EDGES 524288

typedef __attribute__((ext_vector_type(8))) short bf16x8;
typedef __attribute__((ext_vector_type(4))) float f32x4;

__device__ __forceinline__ float bf2f(unsigned short u) {
    union { unsigned int i; float f; } v;
    v.i = ((unsigned int)u) << 16;
    return v.f;
}
__device__ __forceinline__ unsigned short f2bf(float f) {
    union { float f; unsigned int i; } v;
    v.f = f;
    unsigned int r = v.i + 0x7fff + ((v.i >> 16) & 1);  // round-to-nearest-even
    return (unsigned short)(r >> 16);
}

// ---------------- init: cnt=0, logits=0 ---------------------------------------
__global__ void init_k(int* __restrict__ cnt, float* __restrict__ logits) {
    int i = blockIdx.x * 256 + threadIdx.x;
    cnt[i] = 0;
    if (i < 512) logits[i] = 0.0f;
}
__global__ void cnt_k(const int* __restrict__ dst, int* __restrict__ cnt) {
    int e = blockIdx.x * 256 + threadIdx.x;
    atomicAdd(&cnt[dst[e]], 1);
}

// ------- hierarchical exclusive scan of cnt[65536] -> rp, cursor --------------
__global__ __launch_bounds__(256) void scan1_k(const int* __restrict__ cnt,
                                               int* __restrict__ rp,
                                               int* __restrict__ bsum) {
    __shared__ int s[256];
    int t = threadIdx.x, g = blockIdx.x * 256 + t;
    int v = cnt[g];
    s[t] = v;
    __syncthreads();
    for (int d = 1; d < 256; d <<= 1) {
        int u = (t >= d) ? s[t - d] : 0;
        __syncthreads();
        s[t] += u;
        __syncthreads();
    }
    rp[g] = s[t] - v;
    if (t == 255) bsum[blockIdx.x] = s[255];
}
__global__ __launch_bounds__(256) void scan2_k(int* __restrict__ bsum,
                                               int* __restrict__ rp) {
    __shared__ int s[256];
    int t = threadIdx.x;
    int v = bsum[t];
    s[t] = v;
    __syncthreads();
    for (int d = 1; d < 256; d <<= 1) {
        int u = (t >= d) ? s[t - d] : 0;
        __syncthreads();
        s[t] += u;
        __syncthreads();
    }
    bsum[t] = s[t] - v;
    if (t == 255) rp[65536] = s[255];
}
__global__ __launch_bounds__(256) void scan3_k(int* __restrict__ rp,
                                               const int* __restrict__ bsum,
                                               int* __restrict__ cursor) {
    int t = threadIdx.x, g = blockIdx.x * 256 + t;
    int r = rp[g] + bsum[blockIdx.x];
    rp[g] = r;
    cursor[g] = r;
}

// ------- scatter edges into dst-sorted CSR order, packed (src, w) -------------
__global__ void scatter_k(const int* __restrict__ src, const int* __restrict__ dst,
                          const float* __restrict__ w,
                          int* __restrict__ cursor, uint2* __restrict__ ep) {
    int e = blockIdx.x * 256 + threadIdx.x;
    int pos = atomicAdd(&cursor[dst[e]], 1);
    uint2 p;
    p.x = (unsigned int)src[e];
    p.y = __float_as_uint(w[e]);
    ep[pos] = p;
}

// ------- degree from CSR row-sum (coalesced, no atomics) + dinv ---------------
__global__ void rowsum_k(const int* __restrict__ rp, const uint2* __restrict__ ep,
                         float* __restrict__ dinv) {
    int n = blockIdx.x * 256 + threadIdx.x;
    int beg = rp[n], end = rp[n + 1];
    float s = 1.0f;  // self-loop weight
    for (int i = beg; i < end; ++i) s += __uint_as_float(ep[i].y);
    dinv[n] = rsqrtf(s);
}

// ------- x' = bf16(dinv[row] * x) ---------------------------------------------
__global__ void xscale_k(const float* __restrict__ x, const float* __restrict__ dinv,
                         __hip_bfloat16* __restrict__ xbf) {
    int i = (blockIdx.x * 256 + threadIdx.x) * 4;
    float d = dinv[i >> 7];
    float4 v = *(const float4*)(x + i);
    alignas(8) __hip_bfloat16 tmp[4] = {
        __float2bfloat16(d * v.x), __float2bfloat16(d * v.y),
        __float2bfloat16(d * v.z), __float2bfloat16(d * v.w)};
    *(ushort4*)((unsigned short*)xbf + i) = *(const ushort4*)tmp;
}

// ------- weight prep: PACK(wc1) | f2b(wc2) | wcomb PACKED ---------------------
// wc1pk (nkt=64): wc1pk[((nb*64+kt)*64+l)*8+ke] = wc1[nb*16+(l&15)][kt*32+(l>>4)*8+ke]
// WTpk  (nkt=4):  WTpk [((nb*4 +kt)*64+l)*8+ke] = WT [nb*16+(l&15)][kt*32+(l>>4)*8+ke]
__global__ void wprep_k(const float* __restrict__ wc1, __hip_bfloat16* __restrict__ wc1pk,
                        const float* __restrict__ wc2, __hip_bfloat16* __restrict__ wc2bf,
                        const float* __restrict__ w1, const float* __restrict__ wg,
                        __hip_bfloat16* __restrict__ WTpk) {
    int bid = blockIdx.x;
    if (bid < 512) {
        int t = bid * 256 + threadIdx.x;  // [0, 131072)
        int l = t & 63, grp = t >> 6;
        int kt = grp & 63, nb = grp >> 6;
        int n = nb * 16 + (l & 15);
        int k0 = kt * 32 + (l >> 4) * 8;
        const float* src = wc1 + (size_t)n * 2048 + k0;
        alignas(16) __hip_bfloat16 tmp[8];
#pragma unroll
        for (int e = 0; e < 8; ++e) tmp[e] = __float2bfloat16(src[e]);
        *(ushort4*)((unsigned short*)wc1pk + (size_t)t * 8)     = *(const ushort4*)tmp;
        *(ushort4*)((unsigned short*)wc1pk + (size_t)t * 8 + 4) = *(const ushort4*)(tmp + 4);
    } else if (bid < 640) {
        int i = (bid - 512) * 1024 + threadIdx.x * 4;
        float4 v = *(const float4*)(wc2 + i);
        alignas(8) __hip_bfloat16 tmp[4] = {__float2bfloat16(v.x), __float2bfloat16(v.y),
                                            __float2bfloat16(v.z), __float2bfloat16(v.w)};
        *(ushort4*)((unsigned short*)wc2bf + i) = *(const ushort4*)tmp;
    } else {
        int t = (bid - 640) * 256 + threadIdx.x;  // 512*128
        int f = t >> 7, c = t & 127;
        float s = 0.f;
#pragma unroll 8
        for (int m = 0; m < 128; ++m) s += w1[c * 128 + m] * wg[m * 512 + f];
        int pk = ((((f >> 4) * 4 + (c >> 5)) * 64 + ((c >> 3) & 3) * 16 + (f & 15)) * 8) + (c & 7);
        WTpk[pk] = __float2bfloat16(s);
    }
}

// ---------------- gather SpMM, 8-deep ILP pipeline -----------------------------
__global__ __launch_bounds__(256) void gather_k(const int* __restrict__ rp,
                                                const uint2* __restrict__ ep,
                                                const unsigned short* __restrict__ xbf,
                                                const float* __restrict__ dinv,
                                                __hip_bfloat16* __restrict__ ybf) {
    int n = (blockIdx.x * 256 + threadIdx.x) >> 6;
    int lane = threadIdx.x & 63;
    int beg = rp[n], end = rp[n + 1];
    float accx, accy;
    {
        unsigned int u = *(const unsigned int*)(xbf + (size_t)n * 128 + lane * 2);
        accx = bf2f((unsigned short)(u & 0xffff));
        accy = bf2f((unsigned short)(u >> 16));
    }
    int i = beg;
    for (; i + 8 <= end; i += 8) {
        uint2 p[8];
        unsigned int u[8];
#pragma unroll
        for (int k = 0; k < 8; ++k) p[k] = ep[i + k];
#pragma unroll
        for (int k = 0; k < 8; ++k)
            u[k] = *(const unsigned int*)(xbf + (size_t)p[k].x * 128 + lane * 2);
#pragma unroll
        for (int k = 0; k < 8; ++k) {
            float c = __uint_as_float(p[k].y);
            accx += c * bf2f((unsigned short)(u[k] & 0xffff));
            accy += c * bf2f((unsigned short)(u[k] >> 16));
        }
    }
    for (; i + 4 <= end; i += 4) {
        uint2 p[4];
        unsigned int u[4];
#pragma unroll
        for (int k = 0; k < 4; ++k) p[k] = ep[i + k];
#pragma unroll
        for (int k = 0; k < 4; ++k)
            u[k] = *(const unsigned int*)(xbf + (size_t)p[k].x * 128 + lane * 2);
#pragma unroll
        for (int k = 0; k < 4; ++k) {
            float c = __uint_as_float(p[k].y);
            accx += c * bf2f((unsigned short)(u[k] & 0xffff));
            accy += c * bf2f((unsigned short)(u[k] >> 16));
        }
    }
    for (; i < end; ++i) {
        uint2 p = ep[i];
        unsigned int u = *(const unsigned int*)(xbf + (size_t)p.x * 128 + lane * 2);
        float c = __uint_as_float(p.y);
        accx += c * bf2f((unsigned short)(u & 0xffff));
        accy += c * bf2f((unsigned short)(u >> 16));
    }
    float dn = dinv[n];
    accx *= dn;
    accy *= dn;
    alignas(4) __hip_bfloat16 o[2] = {__float2bfloat16(accx), __float2bfloat16(accy)};
    *(unsigned int*)((unsigned short*)ybf + (size_t)n * 128 + lane * 2) =
        *(const unsigned int*)o;
}

// ---------------- async global -> LDS, 16B per lane ---------------------------
__device__ __forceinline__ void gll16(const void* g, void* l) {
    __builtin_amdgcn_global_load_lds(
        (const __attribute__((address_space(1))) void*)g,
        (__attribute__((address_space(3))) void*)l, 16, 0, 0);
}

// ---------------- FUSED h2 + cnn1: BM=32, FULL-WIDTH ht, 2 syncs/segment ------
// act1 = relu(tanh(y@WC+bg) @ wc1^T + bc1). Block = 32 rows (ONE graph),
// 8 waves, 48KB LDS (yt 2x8KB dbuf + ht 32KB full-width) -> 2 blocks/CU.
// Per K-segment g: [syncA] h2 full (4 kt x 4 j) + tanh -> ht[32][1024B]
// [syncC] prefetch yt(g+1) ; 16 BARRIER-FREE cnn1 K-steps (4-deep B ring).
// vs R22: syncs 20 -> 8, barrier-free run 8 -> 16 steps (2x latency cover).
// Layout/swizzles: full-width ht verified in R19; BM=32 grid verified R21;
// yt-dbuf prefetch verified R22. phys16Bslot = s ^ (row&7) on both tiles.
__global__ __launch_bounds__(512) void fh2c1_k(
    const __hip_bfloat16* __restrict__ ybf,   // 65536 x 128
    const __hip_bfloat16* __restrict__ WTpk,  // packed (nkt=4)
    const float* __restrict__ bg,             // 512
    const __hip_bfloat16* __restrict__ wc1pk, // packed (nkt=64)
    const float* __restrict__ bc1,            // 512
    __hip_bfloat16* __restrict__ act1) {      // 16384 x 512
    __shared__ char yt[16384];   // 2 bufs x [32][256B]
    __shared__ char ht[32768];   // [32][1024B] full width
    const int tid = threadIdx.x;
    const int lane = tid & 63, wid = tid >> 6;
    const int bx = blockIdx.x;   // graph index
    const int l15 = lane & 15, lhi = lane >> 4;

    const __hip_bfloat16* Bp[4];
#pragma unroll
    for (int j = 0; j < 4; ++j)
        Bp[j] = wc1pk + ((size_t)(wid * 4 + j) * 64) * 512 + lane * 8;

    // stage: one gll16 per thread into buf (rows wid*4..+3)
    auto stageY = [&](int buf, int g) {
        int r = wid * 4 + (lane >> 4);             // row 0..31 (= e index)
        int node = bx * 128 + g * 32 + r;
        int scol = ((lane & 15) ^ (r & 7)) << 4;   // pre-swizzled source col
        gll16((const char*)ybf + (size_t)node * 256 + scol,
              yt + buf * 8192 + wid * 1024 + lane * 16);
    };

    f32x4 acc[2][4] = {};

    stageY(0, 0);
    __syncthreads();  // vmcnt(0) drained: yt[0] ready

    for (int g = 0; g < 4; ++g) {
        if (g > 0) __syncthreads();  // A: drains yt prefetch + prev cnn1 ht reads
        const char* ytc = yt + (g & 1) * 8192;

        // ---- h2 full width: out[32][512]; wave covers cols wid*64..+63 ----
        f32x4 hacc[2][4] = {};
#pragma unroll
        for (int kt = 0; kt < 4; ++kt) {
            bf16x8 af[2], bfr[4];
#pragma unroll
            for (int i = 0; i < 2; ++i) {
                int r = i * 16 + l15;
                int s = (kt * 4 + lhi) ^ (r & 7);
                af[i] = *(const bf16x8*)(ytc + r * 256 + s * 16);
            }
#pragma unroll
            for (int j = 0; j < 4; ++j) {
                int nb = wid * 4 + j;
                bfr[j] = *(const bf16x8*)(WTpk +
                    ((size_t)(nb * 4 + kt) * 64 + lane) * 8);
            }
#pragma unroll
            for (int i = 0; i < 2; ++i)
#pragma unroll
                for (int j = 0; j < 4; ++j)
                    hacc[i][j] = __builtin_amdgcn_mfma_f32_16x16x32_bf16(
                        bfr[j], af[i], hacc[i][j], 0, 0, 0);
        }
        // ---- tanh + write ht (rows 1024B, swizzled 16B slots) ----
#pragma unroll
        for (int j = 0; j < 4; ++j) {
            int coln = wid * 64 + j * 16 + lhi * 4;
            float4 bgv = *(const float4*)(bg + coln);
            int bytecol = coln * 2;
            int s = bytecol >> 4;
            int off8 = bytecol & 15;  // 0 or 8
#pragma unroll
            for (int i = 0; i < 2; ++i) {
                int row = i * 16 + l15;
                alignas(8) unsigned short o[4];
#pragma unroll
                for (int r = 0; r < 4; ++r) {
                    float v = hacc[i][j][r] + ((const float*)&bgv)[r];
                    v = 1.0f - 2.0f / (__expf(2.0f * v) + 1.0f);  // tanh
                    o[r] = f2bf(v);
                }
                *(uint2*)(ht + row * 1024 + ((s ^ (row & 7)) << 4) + off8) =
                    *(const uint2*)o;
            }
        }
        __syncthreads();  // C: ht ready

        // prefetch next segment's y-tile; lands during the 16-step cnn1 run
        if (g < 3) stageY((g + 1) & 1, g + 1);

        // ---- cnn1 inner: 16 barrier-free K-steps, 4-deep B ring ----
        const int ktb = g * 16;
        bf16x8 bb[4][4];
#pragma unroll
        for (int d = 0; d < 4; ++d)
#pragma unroll
            for (int j = 0; j < 4; ++j)
                bb[d][j] = *(const bf16x8*)(Bp[j] + (size_t)(ktb + d) * 512);
#pragma unroll
        for (int kk = 0; kk < 16; ++kk) {
            bf16x8 af[2];
#pragma unroll
            for (int i = 0; i < 2; ++i) {
                int r = i * 16 + l15;
                int s = (kk * 4 + lhi) ^ (r & 7);
                af[i] = *(const bf16x8*)(ht + r * 1024 + s * 16);
            }
#pragma unroll
            for (int i = 0; i < 2; ++i)
#pragma unroll
                for (int j = 0; j < 4; ++j)
                    acc[i][j] = __builtin_amdgcn_mfma_f32_16x16x32_bf16(
                        bb[kk & 3][j], af[i], acc[i][j], 0, 0, 0);
            if (kk + 4 < 16) {
#pragma unroll
                for (int j = 0; j < 4; ++j)
                    bb[kk & 3][j] =
                        *(const bf16x8*)(Bp[j] + (size_t)(ktb + kk + 4) * 512);
            }
        }
    }

    // ---- epilogue: relu + bias -> act1 (8B ushort4 stores) ----
#pragma unroll
    for (int i = 0; i < 2; ++i) {
        int m = bx * 32 + i * 16 + l15;
#pragma unroll
        for (int j = 0; j < 4; ++j) {
            int n = wid * 64 + j * 16 + lhi * 4;
            float4 bv = *(const float4*)(bc1 + n);
            ushort4 o;
#pragma unroll
            for (int r = 0; r < 4; ++r) {
                float v = fmaxf(acc[i][j][r] + ((const float*)&bv)[r], 0.f);
                ((unsigned short*)&o)[r] = f2bf(v);
            }
            *(ushort4*)((unsigned short*)act1 + (size_t)m * 512 + n) = o;
        }
    }
}

// ---------------- bf16 MFMA GEMM (128x128): cnn2 + final dot ------------------
// R15-verbatim (OUT_MODE 3 path), used only for cnn2+final.
template <int ACT, int OUT_MODE, int SWIZ_NTX>
__global__ __launch_bounds__(256) void gemm_mfma_k(
    const __hip_bfloat16* __restrict__ A, const __hip_bfloat16* __restrict__ B,
    const float* __restrict__ bias, void* __restrict__ Cout,
    const float* __restrict__ wlin, int M, int N, int K) {
    __shared__ char lds[65536];  // 4 bufs x (A 8KB | B 8KB)

    const int tid = threadIdx.x;
    const int lane = tid & 63, wid = tid >> 6;
    int bx, by;
    if (SWIZ_NTX > 0) {
        int orig = blockIdx.x;
        int per = gridDim.x / (8 * SWIZ_NTX);
        int xcd = orig & 7, k = orig >> 3;
        by = xcd * per + k / SWIZ_NTX;
        bx = k % SWIZ_NTX;
    } else {
        bx = blockIdx.x;
        by = blockIdx.y;
    }
    const int bm = by * 128, bn = bx * 128;
    const int wr = wid >> 1, wc = wid & 1;

    const int srow = wid * 16 + (lane >> 2);
    const int skcol = (((lane & 3) ^ ((lane >> 3) & 3))) * 8;
    const __hip_bfloat16* Abase = A + (size_t)(bm + srow) * K + skcol;
    const __hip_bfloat16* Bbase = B + (size_t)(bn + srow) * K + skcol;
    const int ldso = wid * 1024;

    f32x4 acc[4][4] = {};

    const int lrow = lane & 15;
    const int lkb = (((lane >> 4) ^ ((lane >> 1) & 3)) << 4);
    const int nk = K >> 5;

    auto stage = [&](int buf, int kt) {
        char* la = lds + buf * 16384;
        char* lb = la + 8192;
        gll16(Abase + kt * 32,                  la + ldso);
        gll16(Abase + kt * 32 + (size_t)64 * K, la + 4096 + ldso);
        gll16(Bbase + kt * 32,                  lb + ldso);
        gll16(Bbase + kt * 32 + (size_t)64 * K, lb + 4096 + ldso);
    };

    stage(0, 0);
    stage(1, 1);
    stage(2, 2);

    for (int kt = 0; kt < nk; ++kt) {
        int ahead = nk - 1 - kt;
        if (ahead >= 2)      asm volatile("s_waitcnt vmcnt(8)" ::: "memory");
        else if (ahead == 1) asm volatile("s_waitcnt vmcnt(4)" ::: "memory");
        else                 asm volatile("s_waitcnt vmcnt(0)" ::: "memory");
        __builtin_amdgcn_s_barrier();
        asm volatile("" ::: "memory");
        if (kt + 3 < nk) stage((kt + 3) & 3, kt + 3);

        const char* la = lds + (kt & 3) * 16384;
        const char* lb = la + 8192;
        bf16x8 af[4], bfr[4];
#pragma unroll
        for (int i = 0; i < 4; ++i)
            af[i] = *(const bf16x8*)(la + (wr * 64 + i * 16 + lrow) * 64 + lkb);
#pragma unroll
        for (int j = 0; j < 4; ++j)
            bfr[j] = *(const bf16x8*)(lb + (wc * 64 + j * 16 + lrow) * 64 + lkb);
        __builtin_amdgcn_s_setprio(1);
#pragma unroll
        for (int i = 0; i < 4; ++i)
#pragma unroll
            for (int j = 0; j < 4; ++j)
                acc[i][j] = __builtin_amdgcn_mfma_f32_16x16x32_bf16(
                    bfr[j], af[i], acc[i][j], 0, 0, 0);  // SWAPPED operands
        __builtin_amdgcn_s_setprio(0);
        asm volatile("" ::: "memory");
    }

    const int l15 = lane & 15, lhi = lane >> 4;

    if (OUT_MODE == 3) {
        float p0 = 0.f, p1 = 0.f;
#pragma unroll
        for (int i = 0; i < 4; ++i) {
            int e = (i & 1) * 16 + l15;  // m & 31
#pragma unroll
            for (int j = 0; j < 4; ++j) {
                int n = bn + wc * 64 + j * 16 + lhi * 4;
                float4 bv = *(const float4*)(bias + n);
#pragma unroll
                for (int r = 0; r < 4; ++r) {
                    float v = fmaxf(acc[i][j][r] + ((const float*)&bv)[r], 0.f);
                    float wl = wlin[(n + r) * 32 + e];
                    if (i < 2) p0 += v * wl; else p1 += v * wl;
                }
            }
        }
#pragma unroll
        for (int off = 32; off > 0; off >>= 1) {
            p0 += __shfl_down(p0, off, 64);
            p1 += __shfl_down(p1, off, 64);
        }
        if (lane == 0) {
            int g = (bm >> 5) + wr * 2;
            atomicAdd(&((float*)Cout)[g], p0);
            atomicAdd(&((float*)Cout)[g + 1], p1);
        }
        return;
    }

#pragma unroll
    for (int i = 0; i < 4; ++i) {
        int m = bm + wr * 64 + i * 16 + l15;
#pragma unroll
        for (int j = 0; j < 4; ++j) {
            int n = bn + wc * 64 + j * 16 + lhi * 4;
            float4 bv = *(const float4*)(bias + n);
            ushort4 o;
#pragma unroll
            for (int r = 0; r < 4; ++r) {
                float v = acc[i][j][r] + ((const float*)&bv)[r];
                if (ACT == 1) v = fmaxf(v, 0.f);
                ((unsigned short*)&o)[r] = f2bf(v);
            }
            *(ushort4*)((unsigned short*)Cout + (size_t)m * N + n) = o;
        }
    }
}

// ---------------- sigmoid over 512 graph logits --------------------------------
__global__ void sigmoid_k(const float* __restrict__ logits,
                          const float* __restrict__ blin, float* __restrict__ out) {
    int b = blockIdx.x * 256 + threadIdx.x;
    out[b] = 1.0f / (1.0f + expf(-(logits[b] + blin[0])));
}

extern "C" void kernel_launch(void* const* d_in, const int* in_sizes, int n_in,
                              void* d_out, int out_size, void* d_ws, size_t ws_size,
                              hipStream_t stream) {
    const float* x    = (const float*)d_in[0];
    const float* eattr= (const float*)d_in[1];
    const float* w1   = (const float*)d_in[2];
    const float* wg   = (const float*)d_in[3];
    const float* bg   = (const float*)d_in[4];
    const float* wc1  = (const float*)d_in[5];
    const float* bc1  = (const float*)d_in[6];
    const float* wc2  = (const float*)d_in[7];
    const float* bc2  = (const float*)d_in[8];
    const float* wlin = (const float*)d_in[9];
    const float* blin = (const float*)d_in[10];
    const int*   ei   = (const int*)d_in[11];
    const int* esrc = ei;
    const int* edst = ei + N_EDGES;
    float* out = (float*)d_out;

    // workspace layout (bytes, 16B aligned)
    char* ws = (char*)d_ws;
    float*          dinv   = (float*)(ws + 0);          // 262144
    int*            cnt    = (int*)(ws + 262144);       // 262144
    int*            rp     = (int*)(ws + 524288);       // 262160 (65537 ints)
    int*            cursor = (int*)(ws + 786688);       // 262144
    uint2*          ep     = (uint2*)(ws + 1048832);    // 4194304 (packed src,w)
    __hip_bfloat16* WTpk   = (__hip_bfloat16*)(ws + 5243136);   // 131072
    __hip_bfloat16* ybf    = (__hip_bfloat16*)(ws + 5374208);   // 16777216
    __hip_bfloat16* act1   = (__hip_bfloat16*)(ws + 89260288);  // 16777216
    __hip_bfloat16* wc1pk  = (__hip_bfloat16*)(ws + 106037504); // 2097152
    __hip_bfloat16* wc2bf  = (__hip_bfloat16*)(ws + 108134656); // 262144
    __hip_bfloat16* xbf    = (__hip_bfloat16*)(ws + 108396800); // 16777216
    float*          logits = (float*)(ws + 125174016);  // 2048
    int*            bsum   = (int*)(ws + 125176064);    // 1024
    if (ws_size < (size_t)125177088) return;

    // 1) init (cnt=0, logits=0)
    init_k<<<N_NODES / 256, 256, 0, stream>>>(cnt, logits);

    // 2) in-degree counts (int atomics only)
    cnt_k<<<N_EDGES / 256, 256, 0, stream>>>(edst, cnt);

    // 3) hierarchical scan -> rp, cursor
    scan1_k<<<256, 256, 0, stream>>>(cnt, rp, bsum);
    scan2_k<<<1, 256, 0, stream>>>(bsum, rp);
    scan3_k<<<256, 256, 0, stream>>>(rp, bsum, cursor);

    // 4) scatter edges into CSR, packed (src, w) 8B records
    scatter_k<<<N_EDGES / 256, 256, 0, stream>>>(esrc, edst, eattr, cursor, ep);

    // 5) degree via coalesced CSR row-sum -> dinv
    rowsum_k<<<N_NODES / 256, 256, 0, stream>>>(rp, ep, dinv);

    // 6) weight prep (wc1 packed, wc2 bf16, W_comb packed) + x' = bf16(dinv*x)
    wprep_k<<<896, 256, 0, stream>>>(wc1, wc1pk, wc2, wc2bf, w1, wg, WTpk);
    xscale_k<<<(N_NODES * 128 / 4) / 256, 256, 0, stream>>>(x, dinv, xbf);

    // 7) gather SpMM (8-deep ILP) -> ybf
    gather_k<<<N_NODES / 4, 256, 0, stream>>>(rp, ep,
                                              (const unsigned short*)xbf, dinv, ybf);

    // 8) FUSED h2 + cnn1 -> act1 (full-width ht, 2 syncs/segment, 2 blocks/CU)
    fh2c1_k<<<512, 512, 0, stream>>>(ybf, WTpk, bg, wc1pk, bc1, act1);

    // 9) cnn2 + final dot fused
    gemm_mfma_k<1, 3, 0><<<dim3(2, 128), 256, 0, stream>>>(
        act1, wc2bf, bc2, logits, wlin, 16384, 256, 512);

    // 10) sigmoid
    sigmoid_k<<<2, 256, 0, stream>>>(logits, blin, out);
}

// Round 24
// 194.917 us; speedup vs baseline: 1.0832x; 1.0832x over previous
//
#include <hip/hip_runtime.h>
#include <hip/hip_bf16.h>

#define N_NODES 65536
#define N_EDGES 524288

typedef __attribute__((ext_vector_type(8))) short bf16x8;
typedef __attribute__((ext_vector_type(4))) float f32x4;

__device__ __forceinline__ float bf2f(unsigned short u) {
    union { unsigned int i; float f; } v;
    v.i = ((unsigned int)u) << 16;
    return v.f;
}
__device__ __forceinline__ unsigned short f2bf(float f) {
    union { float f; unsigned int i; } v;
    v.f = f;
    unsigned int r = v.i + 0x7fff + ((v.i >> 16) & 1);  // round-to-nearest-even
    return (unsigned short)(r >> 16);
}

// ---------------- init: cnt=0, logits=0 ---------------------------------------
__global__ void init_k(int* __restrict__ cnt, float* __restrict__ logits) {
    int i = blockIdx.x * 256 + threadIdx.x;
    cnt[i] = 0;
    if (i < 512) logits[i] = 0.0f;
}
__global__ void cnt_k(const int* __restrict__ dst, int* __restrict__ cnt) {
    int e = blockIdx.x * 256 + threadIdx.x;
    atomicAdd(&cnt[dst[e]], 1);
}

// ------- hierarchical exclusive scan of cnt[65536] -> rp, cursor --------------
__global__ __launch_bounds__(256) void scan1_k(const int* __restrict__ cnt,
                                               int* __restrict__ rp,
                                               int* __restrict__ bsum) {
    __shared__ int s[256];
    int t = threadIdx.x, g = blockIdx.x * 256 + t;
    int v = cnt[g];
    s[t] = v;
    __syncthreads();
    for (int d = 1; d < 256; d <<= 1) {
        int u = (t >= d) ? s[t - d] : 0;
        __syncthreads();
        s[t] += u;
        __syncthreads();
    }
    rp[g] = s[t] - v;
    if (t == 255) bsum[blockIdx.x] = s[255];
}
__global__ __launch_bounds__(256) void scan2_k(int* __restrict__ bsum,
                                               int* __restrict__ rp) {
    __shared__ int s[256];
    int t = threadIdx.x;
    int v = bsum[t];
    s[t] = v;
    __syncthreads();
    for (int d = 1; d < 256; d <<= 1) {
        int u = (t >= d) ? s[t - d] : 0;
        __syncthreads();
        s[t] += u;
        __syncthreads();
    }
    bsum[t] = s[t] - v;
    if (t == 255) rp[65536] = s[255];
}
__global__ __launch_bounds__(256) void scan3_k(int* __restrict__ rp,
                                               const int* __restrict__ bsum,
                                               int* __restrict__ cursor) {
    int t = threadIdx.x, g = blockIdx.x * 256 + t;
    int r = rp[g] + bsum[blockIdx.x];
    rp[g] = r;
    cursor[g] = r;
}

// ------- scatter edges into dst-sorted CSR order, packed (src, w) -------------
__global__ void scatter_k(const int* __restrict__ src, const int* __restrict__ dst,
                          const float* __restrict__ w,
                          int* __restrict__ cursor, uint2* __restrict__ ep) {
    int e = blockIdx.x * 256 + threadIdx.x;
    int pos = atomicAdd(&cursor[dst[e]], 1);
    uint2 p;
    p.x = (unsigned int)src[e];
    p.y = __float_as_uint(w[e]);
    ep[pos] = p;
}

// ------- degree from CSR row-sum (coalesced, no atomics) + dinv ---------------
__global__ void rowsum_k(const int* __restrict__ rp, const uint2* __restrict__ ep,
                         float* __restrict__ dinv) {
    int n = blockIdx.x * 256 + threadIdx.x;
    int beg = rp[n], end = rp[n + 1];
    float s = 1.0f;  // self-loop weight
    for (int i = beg; i < end; ++i) s += __uint_as_float(ep[i].y);
    dinv[n] = rsqrtf(s);
}

// ------- x' = bf16(dinv[row] * x) ---------------------------------------------
__global__ void xscale_k(const float* __restrict__ x, const float* __restrict__ dinv,
                         __hip_bfloat16* __restrict__ xbf) {
    int i = (blockIdx.x * 256 + threadIdx.x) * 4;
    float d = dinv[i >> 7];
    float4 v = *(const float4*)(x + i);
    alignas(8) __hip_bfloat16 tmp[4] = {
        __float2bfloat16(d * v.x), __float2bfloat16(d * v.y),
        __float2bfloat16(d * v.z), __float2bfloat16(d * v.w)};
    *(ushort4*)((unsigned short*)xbf + i) = *(const ushort4*)tmp;
}

// ------- weight prep: PACK(wc1) | f2b(wc2) | wcomb PACKED ---------------------
// wc1pk (nkt=64): wc1pk[((nb*64+kt)*64+l)*8+ke] = wc1[nb*16+(l&15)][kt*32+(l>>4)*8+ke]
// WTpk  (nkt=4):  WTpk [((nb*4 +kt)*64+l)*8+ke] = WT [nb*16+(l&15)][kt*32+(l>>4)*8+ke]
__global__ void wprep_k(const float* __restrict__ wc1, __hip_bfloat16* __restrict__ wc1pk,
                        const float* __restrict__ wc2, __hip_bfloat16* __restrict__ wc2bf,
                        const float* __restrict__ w1, const float* __restrict__ wg,
                        __hip_bfloat16* __restrict__ WTpk) {
    int bid = blockIdx.x;
    if (bid < 512) {
        int t = bid * 256 + threadIdx.x;  // [0, 131072)
        int l = t & 63, grp = t >> 6;
        int kt = grp & 63, nb = grp >> 6;
        int n = nb * 16 + (l & 15);
        int k0 = kt * 32 + (l >> 4) * 8;
        const float* src = wc1 + (size_t)n * 2048 + k0;
        alignas(16) __hip_bfloat16 tmp[8];
#pragma unroll
        for (int e = 0; e < 8; ++e) tmp[e] = __float2bfloat16(src[e]);
        *(ushort4*)((unsigned short*)wc1pk + (size_t)t * 8)     = *(const ushort4*)tmp;
        *(ushort4*)((unsigned short*)wc1pk + (size_t)t * 8 + 4) = *(const ushort4*)(tmp + 4);
    } else if (bid < 640) {
        int i = (bid - 512) * 1024 + threadIdx.x * 4;
        float4 v = *(const float4*)(wc2 + i);
        alignas(8) __hip_bfloat16 tmp[4] = {__float2bfloat16(v.x), __float2bfloat16(v.y),
                                            __float2bfloat16(v.z), __float2bfloat16(v.w)};
        *(ushort4*)((unsigned short*)wc2bf + i) = *(const ushort4*)tmp;
    } else {
        int t = (bid - 640) * 256 + threadIdx.x;  // 512*128
        int f = t >> 7, c = t & 127;
        float s = 0.f;
#pragma unroll 8
        for (int m = 0; m < 128; ++m) s += w1[c * 128 + m] * wg[m * 512 + f];
        int pk = ((((f >> 4) * 4 + (c >> 5)) * 64 + ((c >> 3) & 3) * 16 + (f & 15)) * 8) + (c & 7);
        WTpk[pk] = __float2bfloat16(s);
    }
}

// ---------------- gather SpMM, 8-deep ILP pipeline -----------------------------
__global__ __launch_bounds__(256) void gather_k(const int* __restrict__ rp,
                                                const uint2* __restrict__ ep,
                                                const unsigned short* __restrict__ xbf,
                                                const float* __restrict__ dinv,
                                                __hip_bfloat16* __restrict__ ybf) {
    int n = (blockIdx.x * 256 + threadIdx.x) >> 6;
    int lane = threadIdx.x & 63;
    int beg = rp[n], end = rp[n + 1];
    float accx, accy;
    {
        unsigned int u = *(const unsigned int*)(xbf + (size_t)n * 128 + lane * 2);
        accx = bf2f((unsigned short)(u & 0xffff));
        accy = bf2f((unsigned short)(u >> 16));
    }
    int i = beg;
    for (; i + 8 <= end; i += 8) {
        uint2 p[8];
        unsigned int u[8];
#pragma unroll
        for (int k = 0; k < 8; ++k) p[k] = ep[i + k];
#pragma unroll
        for (int k = 0; k < 8; ++k)
            u[k] = *(const unsigned int*)(xbf + (size_t)p[k].x * 128 + lane * 2);
#pragma unroll
        for (int k = 0; k < 8; ++k) {
            float c = __uint_as_float(p[k].y);
            accx += c * bf2f((unsigned short)(u[k] & 0xffff));
            accy += c * bf2f((unsigned short)(u[k] >> 16));
        }
    }
    for (; i + 4 <= end; i += 4) {
        uint2 p[4];
        unsigned int u[4];
#pragma unroll
        for (int k = 0; k < 4; ++k) p[k] = ep[i + k];
#pragma unroll
        for (int k = 0; k < 4; ++k)
            u[k] = *(const unsigned int*)(xbf + (size_t)p[k].x * 128 + lane * 2);
#pragma unroll
        for (int k = 0; k < 4; ++k) {
            float c = __uint_as_float(p[k].y);
            accx += c * bf2f((unsigned short)(u[k] & 0xffff));
            accy += c * bf2f((unsigned short)(u[k] >> 16));
        }
    }
    for (; i < end; ++i) {
        uint2 p = ep[i];
        unsigned int u = *(const unsigned int*)(xbf + (size_t)p.x * 128 + lane * 2);
        float c = __uint_as_float(p.y);
        accx += c * bf2f((unsigned short)(u & 0xffff));
        accy += c * bf2f((unsigned short)(u >> 16));
    }
    float dn = dinv[n];
    accx *= dn;
    accy *= dn;
    alignas(4) __hip_bfloat16 o[2] = {__float2bfloat16(accx), __float2bfloat16(accy)};
    *(unsigned int*)((unsigned short*)ybf + (size_t)n * 128 + lane * 2) =
        *(const unsigned int*)o;
}

// ---------------- async global -> LDS, 16B per lane ---------------------------
__device__ __forceinline__ void gll16(const void* g, void* l) {
    __builtin_amdgcn_global_load_lds(
        (const __attribute__((address_space(1))) void*)g,
        (__attribute__((address_space(3))) void*)l, 16, 0, 0);
}

// ---------------- FUSED h2 + cnn1, BM=32, yt-dbuf prefetch + 4-deep B ring ----
// R22 configuration (best measured): act1 = relu(tanh(y@WC+bg) @ wc1^T + bc1).
// Block = 32 rows (ONE graph), 8 waves, 32KB LDS (yt 2x8KB dbuf + ht 16KB)
// -> 2 blocks/CU at VGPR 60. Split-ht (h=0/1 halves) keeps register pressure
// low; yt prefetch for segment g+1 issues under g's h=1 cnn1 phase; cnn1 B
// loads via 4-deep register ring. Swizzle: phys16Bslot = s ^ (row&7).
__global__ __launch_bounds__(512) void fh2c1_k(
    const __hip_bfloat16* __restrict__ ybf,   // 65536 x 128
    const __hip_bfloat16* __restrict__ WTpk,  // packed (nkt=4)
    const float* __restrict__ bg,             // 512
    const __hip_bfloat16* __restrict__ wc1pk, // packed (nkt=64)
    const float* __restrict__ bc1,            // 512
    __hip_bfloat16* __restrict__ act1) {      // 16384 x 512
    __shared__ char yt[16384];   // 2 bufs x [32][256B]
    __shared__ char ht[16384];   // [32][512B]
    const int tid = threadIdx.x;
    const int lane = tid & 63, wid = tid >> 6;
    const int bx = blockIdx.x;   // graph index
    const int l15 = lane & 15, lhi = lane >> 4;

    const __hip_bfloat16* Bp[4];
#pragma unroll
    for (int j = 0; j < 4; ++j)
        Bp[j] = wc1pk + ((size_t)(wid * 4 + j) * 64) * 512 + lane * 8;

    // stage: one gll16 per thread into buf (rows wid*4..+3)
    auto stageY = [&](int buf, int g) {
        int r = wid * 4 + (lane >> 4);             // row 0..31 (= e index)
        int node = bx * 128 + g * 32 + r;
        int scol = ((lane & 15) ^ (r & 7)) << 4;   // pre-swizzled source col
        gll16((const char*)ybf + (size_t)node * 256 + scol,
              yt + buf * 8192 + wid * 1024 + lane * 16);
    };

    f32x4 acc[2][4] = {};

    stageY(0, 0);
    __syncthreads();  // vmcnt(0) drained: yt[0] ready

    for (int g = 0; g < 4; ++g) {
        if (g > 0) __syncthreads();  // drains prefetch gll16 (vmcnt 0) + barrier
        const char* ytc = yt + (g & 1) * 8192;

        for (int h = 0; h < 2; ++h) {
            // ---- h2 half: out[32][256]; wave covers cols h*256+wid*32..+31 ----
            f32x4 hacc[2][2];
#pragma unroll
            for (int i = 0; i < 2; ++i)
#pragma unroll
                for (int j = 0; j < 2; ++j) hacc[i][j] = (f32x4){0.f, 0.f, 0.f, 0.f};
#pragma unroll
            for (int kt = 0; kt < 4; ++kt) {
                bf16x8 af[2], bfr[2];
#pragma unroll
                for (int i = 0; i < 2; ++i) {
                    int r = i * 16 + l15;
                    int s = (kt * 4 + lhi) ^ (r & 7);
                    af[i] = *(const bf16x8*)(ytc + r * 256 + s * 16);
                }
#pragma unroll
                for (int j = 0; j < 2; ++j) {
                    int nb = h * 16 + wid * 2 + j;
                    bfr[j] = *(const bf16x8*)(WTpk +
                        ((size_t)(nb * 4 + kt) * 64 + lane) * 8);
                }
#pragma unroll
                for (int i = 0; i < 2; ++i)
#pragma unroll
                    for (int j = 0; j < 2; ++j)
                        hacc[i][j] = __builtin_amdgcn_mfma_f32_16x16x32_bf16(
                            bfr[j], af[i], hacc[i][j], 0, 0, 0);
            }
            __syncthreads();  // prev inner loop's ht reads done
            // ---- tanh + write ht half (rows 512B, swizzled 16B slots) ----
#pragma unroll
            for (int j = 0; j < 2; ++j) {
                int coln = h * 256 + wid * 32 + j * 16 + lhi * 4;
                float4 bgv = *(const float4*)(bg + coln);
                int bytecol = (wid * 32 + j * 16 + lhi * 4) * 2;  // within 512B row
                int s = bytecol >> 4;
                int off8 = bytecol & 15;  // 0 or 8
#pragma unroll
                for (int i = 0; i < 2; ++i) {
                    int row = i * 16 + l15;
                    alignas(8) unsigned short o[4];
#pragma unroll
                    for (int r = 0; r < 4; ++r) {
                        float v = hacc[i][j][r] + ((const float*)&bgv)[r];
                        v = 1.0f - 2.0f / (__expf(2.0f * v) + 1.0f);  // tanh
                        o[r] = f2bf(v);
                    }
                    *(uint2*)(ht + row * 512 + ((s ^ (row & 7)) << 4) + off8) =
                        *(const uint2*)o;
                }
            }
            __syncthreads();  // ht ready

            // prefetch next segment's y-tile under this cnn1 phase
            if (h == 1 && g < 3) stageY((g + 1) & 1, g + 1);

            // ---- cnn1 inner: 8 barrier-free K-steps, 4-deep B ring ----
            const int ktb = g * 16 + h * 8;
            bf16x8 bb[4][4];
#pragma unroll
            for (int d = 0; d < 4; ++d)
#pragma unroll
                for (int j = 0; j < 4; ++j)
                    bb[d][j] = *(const bf16x8*)(Bp[j] + (size_t)(ktb + d) * 512);
#pragma unroll
            for (int kk = 0; kk < 8; ++kk) {
                bf16x8 af[2];
#pragma unroll
                for (int i = 0; i < 2; ++i) {
                    int r = i * 16 + l15;
                    int s = (kk * 4 + lhi) ^ (r & 7);
                    af[i] = *(const bf16x8*)(ht + r * 512 + s * 16);
                }
#pragma unroll
                for (int i = 0; i < 2; ++i)
#pragma unroll
                    for (int j = 0; j < 4; ++j)
                        acc[i][j] = __builtin_amdgcn_mfma_f32_16x16x32_bf16(
                            bb[kk & 3][j], af[i], acc[i][j], 0, 0, 0);
                if (kk + 4 < 8) {
#pragma unroll
                    for (int j = 0; j < 4; ++j)
                        bb[kk & 3][j] =
                            *(const bf16x8*)(Bp[j] + (size_t)(ktb + kk + 4) * 512);
                }
            }
        }
    }

    // ---- epilogue: relu + bias -> act1 (8B ushort4 stores) ----
#pragma unroll
    for (int i = 0; i < 2; ++i) {
        int m = bx * 32 + i * 16 + l15;
#pragma unroll
        for (int j = 0; j < 4; ++j) {
            int n = wid * 64 + j * 16 + lhi * 4;
            float4 bv = *(const float4*)(bc1 + n);
            ushort4 o;
#pragma unroll
            for (int r = 0; r < 4; ++r) {
                float v = fmaxf(acc[i][j][r] + ((const float*)&bv)[r], 0.f);
                ((unsigned short*)&o)[r] = f2bf(v);
            }
            *(ushort4*)((unsigned short*)act1 + (size_t)m * 512 + n) = o;
        }
    }
}

// ---------------- bf16 MFMA GEMM (128x128): cnn2 + final dot ------------------
// R15-verbatim (OUT_MODE 3 path), used only for cnn2+final.
template <int ACT, int OUT_MODE, int SWIZ_NTX>
__global__ __launch_bounds__(256) void gemm_mfma_k(
    const __hip_bfloat16* __restrict__ A, const __hip_bfloat16* __restrict__ B,
    const float* __restrict__ bias, void* __restrict__ Cout,
    const float* __restrict__ wlin, int M, int N, int K) {
    __shared__ char lds[65536];  // 4 bufs x (A 8KB | B 8KB)

    const int tid = threadIdx.x;
    const int lane = tid & 63, wid = tid >> 6;
    int bx, by;
    if (SWIZ_NTX > 0) {
        int orig = blockIdx.x;
        int per = gridDim.x / (8 * SWIZ_NTX);
        int xcd = orig & 7, k = orig >> 3;
        by = xcd * per + k / SWIZ_NTX;
        bx = k % SWIZ_NTX;
    } else {
        bx = blockIdx.x;
        by = blockIdx.y;
    }
    const int bm = by * 128, bn = bx * 128;
    const int wr = wid >> 1, wc = wid & 1;

    const int srow = wid * 16 + (lane >> 2);
    const int skcol = (((lane & 3) ^ ((lane >> 3) & 3))) * 8;
    const __hip_bfloat16* Abase = A + (size_t)(bm + srow) * K + skcol;
    const __hip_bfloat16* Bbase = B + (size_t)(bn + srow) * K + skcol;
    const int ldso = wid * 1024;

    f32x4 acc[4][4] = {};

    const int lrow = lane & 15;
    const int lkb = (((lane >> 4) ^ ((lane >> 1) & 3)) << 4);
    const int nk = K >> 5;

    auto stage = [&](int buf, int kt) {
        char* la = lds + buf * 16384;
        char* lb = la + 8192;
        gll16(Abase + kt * 32,                  la + ldso);
        gll16(Abase + kt * 32 + (size_t)64 * K, la + 4096 + ldso);
        gll16(Bbase + kt * 32,                  lb + ldso);
        gll16(Bbase + kt * 32 + (size_t)64 * K, lb + 4096 + ldso);
    };

    stage(0, 0);
    stage(1, 1);
    stage(2, 2);

    for (int kt = 0; kt < nk; ++kt) {
        int ahead = nk - 1 - kt;
        if (ahead >= 2)      asm volatile("s_waitcnt vmcnt(8)" ::: "memory");
        else if (ahead == 1) asm volatile("s_waitcnt vmcnt(4)" ::: "memory");
        else                 asm volatile("s_waitcnt vmcnt(0)" ::: "memory");
        __builtin_amdgcn_s_barrier();
        asm volatile("" ::: "memory");
        if (kt + 3 < nk) stage((kt + 3) & 3, kt + 3);

        const char* la = lds + (kt & 3) * 16384;
        const char* lb = la + 8192;
        bf16x8 af[4], bfr[4];
#pragma unroll
        for (int i = 0; i < 4; ++i)
            af[i] = *(const bf16x8*)(la + (wr * 64 + i * 16 + lrow) * 64 + lkb);
#pragma unroll
        for (int j = 0; j < 4; ++j)
            bfr[j] = *(const bf16x8*)(lb + (wc * 64 + j * 16 + lrow) * 64 + lkb);
        __builtin_amdgcn_s_setprio(1);
#pragma unroll
        for (int i = 0; i < 4; ++i)
#pragma unroll
            for (int j = 0; j < 4; ++j)
                acc[i][j] = __builtin_amdgcn_mfma_f32_16x16x32_bf16(
                    bfr[j], af[i], acc[i][j], 0, 0, 0);  // SWAPPED operands
        __builtin_amdgcn_s_setprio(0);
        asm volatile("" ::: "memory");
    }

    const int l15 = lane & 15, lhi = lane >> 4;

    if (OUT_MODE == 3) {
        float p0 = 0.f, p1 = 0.f;
#pragma unroll
        for (int i = 0; i < 4; ++i) {
            int e = (i & 1) * 16 + l15;  // m & 31
#pragma unroll
            for (int j = 0; j < 4; ++j) {
                int n = bn + wc * 64 + j * 16 + lhi * 4;
                float4 bv = *(const float4*)(bias + n);
#pragma unroll
                for (int r = 0; r < 4; ++r) {
                    float v = fmaxf(acc[i][j][r] + ((const float*)&bv)[r], 0.f);
                    float wl = wlin[(n + r) * 32 + e];
                    if (i < 2) p0 += v * wl; else p1 += v * wl;
                }
            }
        }
#pragma unroll
        for (int off = 32; off > 0; off >>= 1) {
            p0 += __shfl_down(p0, off, 64);
            p1 += __shfl_down(p1, off, 64);
        }
        if (lane == 0) {
            int g = (bm >> 5) + wr * 2;
            atomicAdd(&((float*)Cout)[g], p0);
            atomicAdd(&((float*)Cout)[g + 1], p1);
        }
        return;
    }

#pragma unroll
    for (int i = 0; i < 4; ++i) {
        int m = bm + wr * 64 + i * 16 + l15;
#pragma unroll
        for (int j = 0; j < 4; ++j) {
            int n = bn + wc * 64 + j * 16 + lhi * 4;
            float4 bv = *(const float4*)(bias + n);
            ushort4 o;
#pragma unroll
            for (int r = 0; r < 4; ++r) {
                float v = acc[i][j][r] + ((const float*)&bv)[r];
                if (ACT == 1) v = fmaxf(v, 0.f);
                ((unsigned short*)&o)[r] = f2bf(v);
            }
            *(ushort4*)((unsigned short*)Cout + (size_t)m * N + n) = o;
        }
    }
}

// ---------------- sigmoid over 512 graph logits --------------------------------
__global__ void sigmoid_k(const float* __restrict__ logits,
                          const float* __restrict__ blin, float* __restrict__ out) {
    int b = blockIdx.x * 256 + threadIdx.x;
    out[b] = 1.0f / (1.0f + expf(-(logits[b] + blin[0])));
}

extern "C" void kernel_launch(void* const* d_in, const int* in_sizes, int n_in,
                              void* d_out, int out_size, void* d_ws, size_t ws_size,
                              hipStream_t stream) {
    const float* x    = (const float*)d_in[0];
    const float* eattr= (const float*)d_in[1];
    const float* w1   = (const float*)d_in[2];
    const float* wg   = (const float*)d_in[3];
    const float* bg   = (const float*)d_in[4];
    const float* wc1  = (const float*)d_in[5];
    const float* bc1  = (const float*)d_in[6];
    const float* wc2  = (const float*)d_in[7];
    const float* bc2  = (const float*)d_in[8];
    const float* wlin = (const float*)d_in[9];
    const float* blin = (const float*)d_in[10];
    const int*   ei   = (const int*)d_in[11];
    const int* esrc = ei;
    const int* edst = ei + N_EDGES;
    float* out = (float*)d_out;

    // workspace layout (bytes, 16B aligned)
    char* ws = (char*)d_ws;
    float*          dinv   = (float*)(ws + 0);          // 262144
    int*            cnt    = (int*)(ws + 262144);       // 262144
    int*            rp     = (int*)(ws + 524288);       // 262160 (65537 ints)
    int*            cursor = (int*)(ws + 786688);       // 262144
    uint2*          ep     = (uint2*)(ws + 1048832);    // 4194304 (packed src,w)
    __hip_bfloat16* WTpk   = (__hip_bfloat16*)(ws + 5243136);   // 131072
    __hip_bfloat16* ybf    = (__hip_bfloat16*)(ws + 5374208);   // 16777216
    __hip_bfloat16* act1   = (__hip_bfloat16*)(ws + 89260288);  // 16777216
    __hip_bfloat16* wc1pk  = (__hip_bfloat16*)(ws + 106037504); // 2097152
    __hip_bfloat16* wc2bf  = (__hip_bfloat16*)(ws + 108134656); // 262144
    __hip_bfloat16* xbf    = (__hip_bfloat16*)(ws + 108396800); // 16777216
    float*          logits = (float*)(ws + 125174016);  // 2048
    int*            bsum   = (int*)(ws + 125176064);    // 1024
    if (ws_size < (size_t)125177088) return;

    // 1) init (cnt=0, logits=0)
    init_k<<<N_NODES / 256, 256, 0, stream>>>(cnt, logits);

    // 2) in-degree counts (int atomics only)
    cnt_k<<<N_EDGES / 256, 256, 0, stream>>>(edst, cnt);

    // 3) hierarchical scan -> rp, cursor
    scan1_k<<<256, 256, 0, stream>>>(cnt, rp, bsum);
    scan2_k<<<1, 256, 0, stream>>>(bsum, rp);
    scan3_k<<<256, 256, 0, stream>>>(rp, bsum, cursor);

    // 4) scatter edges into CSR, packed (src, w) 8B records
    scatter_k<<<N_EDGES / 256, 256, 0, stream>>>(esrc, edst, eattr, cursor, ep);

    // 5) degree via coalesced CSR row-sum -> dinv
    rowsum_k<<<N_NODES / 256, 256, 0, stream>>>(rp, ep, dinv);

    // 6) weight prep (wc1 packed, wc2 bf16, W_comb packed) + x' = bf16(dinv*x)
    wprep_k<<<896, 256, 0, stream>>>(wc1, wc1pk, wc2, wc2bf, w1, wg, WTpk);
    xscale_k<<<(N_NODES * 128 / 4) / 256, 256, 0, stream>>>(x, dinv, xbf);

    // 7) gather SpMM (8-deep ILP) -> ybf
    gather_k<<<N_NODES / 4, 256, 0, stream>>>(rp, ep,
                                              (const unsigned short*)xbf, dinv, ybf);

    // 8) FUSED h2 + cnn1 -> act1 (yt-dbuf prefetch + 4-deep B ring)
    fh2c1_k<<<512, 512, 0, stream>>>(ybf, WTpk, bg, wc1pk, bc1, act1);

    // 9) cnn2 + final dot fused
    gemm_mfma_k<1, 3, 0><<<dim3(2, 128), 256, 0, stream>>>(
        act1, wc2bf, bc2, logits, wlin, 16384, 256, 512);

    // 10) sigmoid
    sigmoid_k<<<2, 256, 0, stream>>>(logits, blin, out);
}

// Round 25
// 186.080 us; speedup vs baseline: 1.1347x; 1.0475x over previous
//
#include <hip/hip_runtime.h>
#include <hip/hip_bf16.h>

#define N_NODES 65536
#define N_EDGES 524288

typedef __attribute__((ext_vector_type(8))) short bf16x8;
typedef __attribute__((ext_vector_type(4))) float f32x4;

__device__ __forceinline__ float bf2f(unsigned short u) {
    union { unsigned int i; float f; } v;
    v.i = ((unsigned int)u) << 16;
    return v.f;
}
__device__ __forceinline__ unsigned short f2bf(float f) {
    union { float f; unsigned int i; } v;
    v.f = f;
    unsigned int r = v.i + 0x7fff + ((v.i >> 16) & 1);  // round-to-nearest-even
    return (unsigned short)(r >> 16);
}

// ---------------- init: cnt=0 ---------------------------------------------------
__global__ void init_k(int* __restrict__ cnt) {
    cnt[blockIdx.x * 256 + threadIdx.x] = 0;
}
__global__ void cnt_k(const int* __restrict__ dst, int* __restrict__ cnt) {
    int e = blockIdx.x * 256 + threadIdx.x;
    atomicAdd(&cnt[dst[e]], 1);
}

// ------- hierarchical exclusive scan of cnt[65536] -> rp, cursor --------------
__global__ __launch_bounds__(256) void scan1_k(const int* __restrict__ cnt,
                                               int* __restrict__ rp,
                                               int* __restrict__ bsum) {
    __shared__ int s[256];
    int t = threadIdx.x, g = blockIdx.x * 256 + t;
    int v = cnt[g];
    s[t] = v;
    __syncthreads();
    for (int d = 1; d < 256; d <<= 1) {
        int u = (t >= d) ? s[t - d] : 0;
        __syncthreads();
        s[t] += u;
        __syncthreads();
    }
    rp[g] = s[t] - v;
    if (t == 255) bsum[blockIdx.x] = s[255];
}
__global__ __launch_bounds__(256) void scan2_k(int* __restrict__ bsum,
                                               int* __restrict__ rp) {
    __shared__ int s[256];
    int t = threadIdx.x;
    int v = bsum[t];
    s[t] = v;
    __syncthreads();
    for (int d = 1; d < 256; d <<= 1) {
        int u = (t >= d) ? s[t - d] : 0;
        __syncthreads();
        s[t] += u;
        __syncthreads();
    }
    bsum[t] = s[t] - v;
    if (t == 255) rp[65536] = s[255];
}
__global__ __launch_bounds__(256) void scan3_k(int* __restrict__ rp,
                                               const int* __restrict__ bsum,
                                               int* __restrict__ cursor) {
    int t = threadIdx.x, g = blockIdx.x * 256 + t;
    int r = rp[g] + bsum[blockIdx.x];
    rp[g] = r;
    cursor[g] = r;
}

// ------- scatter edges into dst-sorted CSR order, packed (src, w) -------------
__global__ void scatter_k(const int* __restrict__ src, const int* __restrict__ dst,
                          const float* __restrict__ w,
                          int* __restrict__ cursor, uint2* __restrict__ ep) {
    int e = blockIdx.x * 256 + threadIdx.x;
    int pos = atomicAdd(&cursor[dst[e]], 1);
    uint2 p;
    p.x = (unsigned int)src[e];
    p.y = __float_as_uint(w[e]);
    ep[pos] = p;
}

// ------- degree from CSR row-sum (coalesced, no atomics) + dinv ---------------
__global__ void rowsum_k(const int* __restrict__ rp, const uint2* __restrict__ ep,
                         float* __restrict__ dinv) {
    int n = blockIdx.x * 256 + threadIdx.x;
    int beg = rp[n], end = rp[n + 1];
    float s = 1.0f;  // self-loop weight
    for (int i = beg; i < end; ++i) s += __uint_as_float(ep[i].y);
    dinv[n] = rsqrtf(s);
}

// ------- x' = bf16(dinv[row] * x) ---------------------------------------------
__global__ void xscale_k(const float* __restrict__ x, const float* __restrict__ dinv,
                         __hip_bfloat16* __restrict__ xbf) {
    int i = (blockIdx.x * 256 + threadIdx.x) * 4;
    float d = dinv[i >> 7];
    float4 v = *(const float4*)(x + i);
    alignas(8) __hip_bfloat16 tmp[4] = {
        __float2bfloat16(d * v.x), __float2bfloat16(d * v.y),
        __float2bfloat16(d * v.z), __float2bfloat16(d * v.w)};
    *(ushort4*)((unsigned short*)xbf + i) = *(const ushort4*)tmp;
}

// ------- weight prep: PACK(wc1) | PACK(wc2) | wcomb PACKED --------------------
// pack (N x K weights, (out,in)):
//   pk[((nb*nkt+kt)*64+l)*8+ke] = W[nb*16+(l&15)][kt*32+(l>>4)*8+ke]
// wc1: K=2048 nkt=64 (blocks [0,512)); wc2: K=512 nkt=16 (blocks [512,576));
// wcomb: computed, packed nkt=4 (blocks [576,832)).
__global__ void wprep_k(const float* __restrict__ wc1, __hip_bfloat16* __restrict__ wc1pk,
                        const float* __restrict__ wc2, __hip_bfloat16* __restrict__ wc2pk,
                        const float* __restrict__ w1, const float* __restrict__ wg,
                        __hip_bfloat16* __restrict__ WTpk) {
    int bid = blockIdx.x;
    if (bid < 576) {
        const float* W;
        __hip_bfloat16* outp;
        int t, K, nkt;
        if (bid < 512) { W = wc1; outp = wc1pk; t = bid * 256 + threadIdx.x; K = 2048; nkt = 64; }
        else           { W = wc2; outp = wc2pk; t = (bid - 512) * 256 + threadIdx.x; K = 512; nkt = 16; }
        int l = t & 63, grp = t >> 6;
        int kt = grp % nkt, nb = grp / nkt;
        int n = nb * 16 + (l & 15);
        int k0 = kt * 32 + (l >> 4) * 8;
        const float* src = W + (size_t)n * K + k0;
        alignas(16) __hip_bfloat16 tmp[8];
#pragma unroll
        for (int e = 0; e < 8; ++e) tmp[e] = __float2bfloat16(src[e]);
        *(ushort4*)((unsigned short*)outp + (size_t)t * 8)     = *(const ushort4*)tmp;
        *(ushort4*)((unsigned short*)outp + (size_t)t * 8 + 4) = *(const ushort4*)(tmp + 4);
    } else {
        int t = (bid - 576) * 256 + threadIdx.x;  // 512*128
        int f = t >> 7, c = t & 127;
        float s = 0.f;
#pragma unroll 8
        for (int m = 0; m < 128; ++m) s += w1[c * 128 + m] * wg[m * 512 + f];
        int pk = ((((f >> 4) * 4 + (c >> 5)) * 64 + ((c >> 3) & 3) * 16 + (f & 15)) * 8) + (c & 7);
        WTpk[pk] = __float2bfloat16(s);
    }
}

// ---------------- gather SpMM, 8-deep ILP pipeline -----------------------------
__global__ __launch_bounds__(256) void gather_k(const int* __restrict__ rp,
                                                const uint2* __restrict__ ep,
                                                const unsigned short* __restrict__ xbf,
                                                const float* __restrict__ dinv,
                                                __hip_bfloat16* __restrict__ ybf) {
    int n = (blockIdx.x * 256 + threadIdx.x) >> 6;
    int lane = threadIdx.x & 63;
    int beg = rp[n], end = rp[n + 1];
    float accx, accy;
    {
        unsigned int u = *(const unsigned int*)(xbf + (size_t)n * 128 + lane * 2);
        accx = bf2f((unsigned short)(u & 0xffff));
        accy = bf2f((unsigned short)(u >> 16));
    }
    int i = beg;
    for (; i + 8 <= end; i += 8) {
        uint2 p[8];
        unsigned int u[8];
#pragma unroll
        for (int k = 0; k < 8; ++k) p[k] = ep[i + k];
#pragma unroll
        for (int k = 0; k < 8; ++k)
            u[k] = *(const unsigned int*)(xbf + (size_t)p[k].x * 128 + lane * 2);
#pragma unroll
        for (int k = 0; k < 8; ++k) {
            float c = __uint_as_float(p[k].y);
            accx += c * bf2f((unsigned short)(u[k] & 0xffff));
            accy += c * bf2f((unsigned short)(u[k] >> 16));
        }
    }
    for (; i + 4 <= end; i += 4) {
        uint2 p[4];
        unsigned int u[4];
#pragma unroll
        for (int k = 0; k < 4; ++k) p[k] = ep[i + k];
#pragma unroll
        for (int k = 0; k < 4; ++k)
            u[k] = *(const unsigned int*)(xbf + (size_t)p[k].x * 128 + lane * 2);
#pragma unroll
        for (int k = 0; k < 4; ++k) {
            float c = __uint_as_float(p[k].y);
            accx += c * bf2f((unsigned short)(u[k] & 0xffff));
            accy += c * bf2f((unsigned short)(u[k] >> 16));
        }
    }
    for (; i < end; ++i) {
        uint2 p = ep[i];
        unsigned int u = *(const unsigned int*)(xbf + (size_t)p.x * 128 + lane * 2);
        float c = __uint_as_float(p.y);
        accx += c * bf2f((unsigned short)(u & 0xffff));
        accy += c * bf2f((unsigned short)(u >> 16));
    }
    float dn = dinv[n];
    accx *= dn;
    accy *= dn;
    alignas(4) __hip_bfloat16 o[2] = {__float2bfloat16(accx), __float2bfloat16(accy)};
    *(unsigned int*)((unsigned short*)ybf + (size_t)n * 128 + lane * 2) =
        *(const unsigned int*)o;
}

// ---------------- async global -> LDS, 16B per lane ---------------------------
__device__ __forceinline__ void gll16(const void* g, void* l) {
    __builtin_amdgcn_global_load_lds(
        (const __attribute__((address_space(1))) void*)g,
        (__attribute__((address_space(3))) void*)l, 16, 0, 0);
}

// ---------------- FULLY-FUSED h2 + cnn1 + cnn2 + final + sigmoid --------------
// Block = ONE graph (32 act1 rows), 8 waves, 32KB LDS + 32B reduce scratch.
// Body: R22's verified split-ht structure (yt 2x8KB dbuf + ht 16KB, 2 blk/CU,
// yt prefetch under cnn1, 4-deep B ring). NEW TAIL: the block's full act1
// tile (32x512) is spilled (relu'd, bf16) to the now-dead 32KB LDS, then a
// 16-step cnn2 sub-GEMM (wc2 packed bursts) + bc2/relu + wlin dot + block
// reduce + sigmoid writes out[graph] directly -- cnn2/sigmoid dispatches and
// the 32MB act1 HBM round-trip are eliminated.
// Swizzle everywhere: phys16Bslot = s ^ (row&7).
__global__ __launch_bounds__(512) void fh2c1_k(
    const __hip_bfloat16* __restrict__ ybf,   // 65536 x 128
    const __hip_bfloat16* __restrict__ WTpk,  // packed (nkt=4)
    const float* __restrict__ bg,             // 512
    const __hip_bfloat16* __restrict__ wc1pk, // packed (nkt=64)
    const float* __restrict__ bc1,            // 512
    const __hip_bfloat16* __restrict__ wc2pk, // packed (nkt=16)
    const float* __restrict__ bc2,            // 256
    const float* __restrict__ wlin,           // 8192
    const float* __restrict__ blin,           // 1
    float* __restrict__ out) {                // 512
    __shared__ char lds[32768];  // [0,16K): yt 2x8KB ; [16K,32K): ht ; tail: at[32][1024B]
    __shared__ float red[8];
    char* yt = lds;
    char* ht = lds + 16384;
    const int tid = threadIdx.x;
    const int lane = tid & 63, wid = tid >> 6;
    const int bx = blockIdx.x;   // graph index
    const int l15 = lane & 15, lhi = lane >> 4;

    const __hip_bfloat16* Bp[4];
#pragma unroll
    for (int j = 0; j < 4; ++j)
        Bp[j] = wc1pk + ((size_t)(wid * 4 + j) * 64) * 512 + lane * 8;

    // stage: one gll16 per thread into buf (rows wid*4..+3)
    auto stageY = [&](int buf, int g) {
        int r = wid * 4 + (lane >> 4);             // row 0..31 (= e index)
        int node = bx * 128 + g * 32 + r;
        int scol = ((lane & 15) ^ (r & 7)) << 4;   // pre-swizzled source col
        gll16((const char*)ybf + (size_t)node * 256 + scol,
              yt + buf * 8192 + wid * 1024 + lane * 16);
    };

    f32x4 acc[2][4] = {};

    stageY(0, 0);
    __syncthreads();  // vmcnt(0) drained: yt[0] ready

    for (int g = 0; g < 4; ++g) {
        if (g > 0) __syncthreads();  // drains prefetch gll16 (vmcnt 0) + barrier
        const char* ytc = yt + (g & 1) * 8192;

        for (int h = 0; h < 2; ++h) {
            // ---- h2 half: out[32][256]; wave covers cols h*256+wid*32..+31 ----
            f32x4 hacc[2][2];
#pragma unroll
            for (int i = 0; i < 2; ++i)
#pragma unroll
                for (int j = 0; j < 2; ++j) hacc[i][j] = (f32x4){0.f, 0.f, 0.f, 0.f};
#pragma unroll
            for (int kt = 0; kt < 4; ++kt) {
                bf16x8 af[2], bfr[2];
#pragma unroll
                for (int i = 0; i < 2; ++i) {
                    int r = i * 16 + l15;
                    int s = (kt * 4 + lhi) ^ (r & 7);
                    af[i] = *(const bf16x8*)(ytc + r * 256 + s * 16);
                }
#pragma unroll
                for (int j = 0; j < 2; ++j) {
                    int nb = h * 16 + wid * 2 + j;
                    bfr[j] = *(const bf16x8*)(WTpk +
                        ((size_t)(nb * 4 + kt) * 64 + lane) * 8);
                }
#pragma unroll
                for (int i = 0; i < 2; ++i)
#pragma unroll
                    for (int j = 0; j < 2; ++j)
                        hacc[i][j] = __builtin_amdgcn_mfma_f32_16x16x32_bf16(
                            bfr[j], af[i], hacc[i][j], 0, 0, 0);
            }
            __syncthreads();  // prev inner loop's ht reads done
            // ---- tanh + write ht half (rows 512B, swizzled 16B slots) ----
#pragma unroll
            for (int j = 0; j < 2; ++j) {
                int coln = h * 256 + wid * 32 + j * 16 + lhi * 4;
                float4 bgv = *(const float4*)(bg + coln);
                int bytecol = (wid * 32 + j * 16 + lhi * 4) * 2;  // within 512B row
                int s = bytecol >> 4;
                int off8 = bytecol & 15;  // 0 or 8
#pragma unroll
                for (int i = 0; i < 2; ++i) {
                    int row = i * 16 + l15;
                    alignas(8) unsigned short o[4];
#pragma unroll
                    for (int r = 0; r < 4; ++r) {
                        float v = hacc[i][j][r] + ((const float*)&bgv)[r];
                        v = 1.0f - 2.0f / (__expf(2.0f * v) + 1.0f);  // tanh
                        o[r] = f2bf(v);
                    }
                    *(uint2*)(ht + row * 512 + ((s ^ (row & 7)) << 4) + off8) =
                        *(const uint2*)o;
                }
            }
            __syncthreads();  // ht ready

            // prefetch next segment's y-tile under this cnn1 phase
            if (h == 1 && g < 3) stageY((g + 1) & 1, g + 1);

            // ---- cnn1 inner: 8 barrier-free K-steps, 4-deep B ring ----
            const int ktb = g * 16 + h * 8;
            bf16x8 bb[4][4];
#pragma unroll
            for (int d = 0; d < 4; ++d)
#pragma unroll
                for (int j = 0; j < 4; ++j)
                    bb[d][j] = *(const bf16x8*)(Bp[j] + (size_t)(ktb + d) * 512);
#pragma unroll
            for (int kk = 0; kk < 8; ++kk) {
                bf16x8 af[2];
#pragma unroll
                for (int i = 0; i < 2; ++i) {
                    int r = i * 16 + l15;
                    int s = (kk * 4 + lhi) ^ (r & 7);
                    af[i] = *(const bf16x8*)(ht + r * 512 + s * 16);
                }
#pragma unroll
                for (int i = 0; i < 2; ++i)
#pragma unroll
                    for (int j = 0; j < 4; ++j)
                        acc[i][j] = __builtin_amdgcn_mfma_f32_16x16x32_bf16(
                            bb[kk & 3][j], af[i], acc[i][j], 0, 0, 0);
                if (kk + 4 < 8) {
#pragma unroll
                    for (int j = 0; j < 4; ++j)
                        bb[kk & 3][j] =
                            *(const bf16x8*)(Bp[j] + (size_t)(ktb + kk + 4) * 512);
                }
            }
        }
    }

    // ======================= fused cnn2 + final + sigmoid ======================
    __syncthreads();  // all cnn1 ht reads retired; LDS free for reuse
    char* at = lds;   // act1 tile [32 rows][1024B], swizzled like ht/R19

    // ---- spill act1 = relu(acc + bc1) to LDS (bf16, 8B writes) ----
#pragma unroll
    for (int j = 0; j < 4; ++j) {
        int coln = wid * 64 + j * 16 + lhi * 4;
        float4 bv = *(const float4*)(bc1 + coln);
        int bytecol = coln * 2;
        int s = bytecol >> 4;
        int off8 = bytecol & 15;  // 0 or 8
#pragma unroll
        for (int i = 0; i < 2; ++i) {
            int row = i * 16 + l15;
            alignas(8) unsigned short o[4];
#pragma unroll
            for (int r = 0; r < 4; ++r) {
                float v = fmaxf(acc[i][j][r] + ((const float*)&bv)[r], 0.f);
                o[r] = f2bf(v);
            }
            *(uint2*)(at + row * 1024 + ((s ^ (row & 7)) << 4) + off8) =
                *(const uint2*)o;
        }
    }
    __syncthreads();  // act1 tile ready

    // ---- cnn2 sub-GEMM: 32 x 256, K=512 (16 steps); wave -> cols wid*32..+31 ----
    const __hip_bfloat16* Cp[2];
#pragma unroll
    for (int j = 0; j < 2; ++j)
        Cp[j] = wc2pk + ((size_t)(wid * 2 + j) * 16) * 512 + lane * 8;
    f32x4 cacc[2][2];
#pragma unroll
    for (int i = 0; i < 2; ++i)
#pragma unroll
        for (int j = 0; j < 2; ++j) cacc[i][j] = (f32x4){0.f, 0.f, 0.f, 0.f};
#pragma unroll
    for (int kt = 0; kt < 16; ++kt) {
        bf16x8 af[2], bfr[2];
#pragma unroll
        for (int i = 0; i < 2; ++i) {
            int r = i * 16 + l15;
            int s = (kt * 4 + lhi) ^ (r & 7);
            af[i] = *(const bf16x8*)(at + r * 1024 + s * 16);
        }
#pragma unroll
        for (int j = 0; j < 2; ++j)
            bfr[j] = *(const bf16x8*)(Cp[j] + (size_t)kt * 512);
#pragma unroll
        for (int i = 0; i < 2; ++i)
#pragma unroll
            for (int j = 0; j < 2; ++j)
                cacc[i][j] = __builtin_amdgcn_mfma_f32_16x16x32_bf16(
                    bfr[j], af[i], cacc[i][j], 0, 0, 0);
    }

    // ---- final dot: part = sum relu(cacc + bc2) * wlin[p*32 + e] ----
    float part = 0.f;
#pragma unroll
    for (int i = 0; i < 2; ++i) {
        int e = i * 16 + l15;
#pragma unroll
        for (int j = 0; j < 2; ++j) {
            int p = wid * 32 + j * 16 + lhi * 4;
            float4 bv = *(const float4*)(bc2 + p);
#pragma unroll
            for (int r = 0; r < 4; ++r) {
                float v = fmaxf(cacc[i][j][r] + ((const float*)&bv)[r], 0.f);
                part += v * wlin[(p + r) * 32 + e];
            }
        }
    }
#pragma unroll
    for (int off = 32; off > 0; off >>= 1) part += __shfl_down(part, off, 64);
    if (lane == 0) red[wid] = part;
    __syncthreads();
    if (tid == 0) {
        float tot = blin[0];
#pragma unroll
        for (int w = 0; w < 8; ++w) tot += red[w];
        out[bx] = 1.0f / (1.0f + __expf(-tot));
    }
}

extern "C" void kernel_launch(void* const* d_in, const int* in_sizes, int n_in,
                              void* d_out, int out_size, void* d_ws, size_t ws_size,
                              hipStream_t stream) {
    const float* x    = (const float*)d_in[0];
    const float* eattr= (const float*)d_in[1];
    const float* w1   = (const float*)d_in[2];
    const float* wg   = (const float*)d_in[3];
    const float* bg   = (const float*)d_in[4];
    const float* wc1  = (const float*)d_in[5];
    const float* bc1  = (const float*)d_in[6];
    const float* wc2  = (const float*)d_in[7];
    const float* bc2  = (const float*)d_in[8];
    const float* wlin = (const float*)d_in[9];
    const float* blin = (const float*)d_in[10];
    const int*   ei   = (const int*)d_in[11];
    const int* esrc = ei;
    const int* edst = ei + N_EDGES;
    float* out = (float*)d_out;

    // workspace layout (bytes, 16B aligned)
    char* ws = (char*)d_ws;
    float*          dinv   = (float*)(ws + 0);          // 262144
    int*            cnt    = (int*)(ws + 262144);       // 262144
    int*            rp     = (int*)(ws + 524288);       // 262160 (65537 ints)
    int*            cursor = (int*)(ws + 786688);       // 262144
    uint2*          ep     = (uint2*)(ws + 1048832);    // 4194304 (packed src,w)
    __hip_bfloat16* WTpk   = (__hip_bfloat16*)(ws + 5243136);   // 131072
    __hip_bfloat16* ybf    = (__hip_bfloat16*)(ws + 5374208);   // 16777216
    __hip_bfloat16* wc1pk  = (__hip_bfloat16*)(ws + 22151424);  // 2097152
    __hip_bfloat16* wc2pk  = (__hip_bfloat16*)(ws + 24248576);  // 262144
    __hip_bfloat16* xbf    = (__hip_bfloat16*)(ws + 24510720);  // 16777216
    int*            bsum   = (int*)(ws + 41287936);     // 1024
    if (ws_size < (size_t)41288960) return;

    // 1) init (cnt=0)
    init_k<<<N_NODES / 256, 256, 0, stream>>>(cnt);

    // 2) in-degree counts (int atomics only)
    cnt_k<<<N_EDGES / 256, 256, 0, stream>>>(edst, cnt);

    // 3) hierarchical scan -> rp, cursor
    scan1_k<<<256, 256, 0, stream>>>(cnt, rp, bsum);
    scan2_k<<<1, 256, 0, stream>>>(bsum, rp);
    scan3_k<<<256, 256, 0, stream>>>(rp, bsum, cursor);

    // 4) scatter edges into CSR, packed (src, w) 8B records
    scatter_k<<<N_EDGES / 256, 256, 0, stream>>>(esrc, edst, eattr, cursor, ep);

    // 5) degree via coalesced CSR row-sum -> dinv
    rowsum_k<<<N_NODES / 256, 256, 0, stream>>>(rp, ep, dinv);

    // 6) weight prep (wc1/wc2 packed, W_comb packed) + x' = bf16(dinv * x)
    wprep_k<<<832, 256, 0, stream>>>(wc1, wc1pk, wc2, wc2pk, w1, wg, WTpk);
    xscale_k<<<(N_NODES * 128 / 4) / 256, 256, 0, stream>>>(x, dinv, xbf);

    // 7) gather SpMM (8-deep ILP) -> ybf
    gather_k<<<N_NODES / 4, 256, 0, stream>>>(rp, ep,
                                              (const unsigned short*)xbf, dinv, ybf);

    // 8) FULLY-FUSED h2 + cnn1 + cnn2 + final + sigmoid -> out (one kernel)
    fh2c1_k<<<512, 512, 0, stream>>>(ybf, WTpk, bg, wc1pk, bc1,
                                     wc2pk, bc2, wlin, blin, out);
}